// Round 5
// baseline (4509.995 us; speedup 1.0000x reference)
//
#include <hip/hip_runtime.h>
#include <math.h>

#define DEVFN __device__ __forceinline__

namespace {

constexpr int NW = 320, NH = 320, NHW = NW * NH, NB = 4;
constexpr int NC2 = 2 * NHW;          // floats per complex image (planar re/im)
constexpr int GRID = NB * NH;         // 1280 blocks (one line per block)
constexpr int NTHR = 320;             // one point per thread
constexpr float THRESHc = 0.01f;      // LAMBDA_TV / RHO

struct C2 { float x, y; };
DEVFN C2 cmul(C2 a, C2 b) { return C2{a.x * b.x - a.y * b.y, a.x * b.y + a.y * b.x}; }

template <int SIGN>
DEVFN C2 TW(const float2* __restrict__ tw, int m) {
  float2 t = tw[m];
  return C2{t.x, (SIGN < 0) ? t.y : -t.y};
}

// XCD-chunked swizzle for column kernels: adjacent columns -> same XCD L2
DEVFN int swzcol(int bid) { return (bid & 7) * (GRID / 8) + (bid >> 3); }

// 320-pt FFT, 320 threads (1 point each), mixed radix 5*4*4*4.
// Input: A natural order (caller fills sA[t], fftp starts with sync).
// Output: A natural order (trailing sync included). tw = cis(-2*pi*m/320), global.
// MASKED: multiply final-stage register value by misRow[5*n1+q] before store.
template <int SIGN, bool MASKED>
__device__ void fftp(float2* A, float2* B, const float2* __restrict__ tw, int t,
                     const float* __restrict__ misRow) {
  const int q = t >> 6, n1 = t & 63;
  __syncthreads();  // A ready
  C2 acc;
  {  // radix-5 over stride-64 + twiddle w320^{n1 q}
    float2 v0 = A[n1];
    acc.x = v0.x; acc.y = v0.y;
#pragma unroll
    for (int n2 = 1; n2 < 5; n2++) {
      float2 v = A[n1 + 64 * n2];
      C2 w = TW<SIGN>(tw, 64 * ((n2 * q) % 5));
      acc.x += v.x * w.x - v.y * w.y;
      acc.y += v.x * w.y + v.y * w.x;
    }
    acc = cmul(acc, TW<SIGN>(tw, n1 * q));  // n1*q <= 252 < 320
  }
  B[t] = make_float2(acc.x, acc.y);
  __syncthreads();
  {  // radix-4, Lr=4 (w4 = tw[80*..])
    C2 s{0.f, 0.f};
    int rr = n1 & 3, base = (q << 6) + (n1 >> 2);
#pragma unroll
    for (int p = 0; p < 4; p++) {
      float2 v = B[base + 16 * p];
      C2 w = TW<SIGN>(tw, 80 * ((p * rr) & 3));
      s.x += v.x * w.x - v.y * w.y;
      s.y += v.x * w.y + v.y * w.x;
    }
    acc = s;
  }
  A[t] = make_float2(acc.x, acc.y);
  __syncthreads();
  {  // radix-4, Lr=16 (w16 = tw[20*..])
    C2 s{0.f, 0.f};
    int rr = n1 & 15, base = (q << 6) + ((n1 >> 4) << 2) + (n1 & 3);
#pragma unroll
    for (int p = 0; p < 4; p++) {
      float2 v = A[base + 16 * p];
      C2 w = TW<SIGN>(tw, 20 * ((p * rr) & 15));
      s.x += v.x * w.x - v.y * w.y;
      s.y += v.x * w.y + v.y * w.x;
    }
    acc = s;
  }
  B[t] = make_float2(acc.x, acc.y);
  __syncthreads();
  {  // radix-4, Lr=64 (w64 = tw[5*..]) -> output index 5*n1+q
    C2 s{0.f, 0.f};
    int base = (q << 6) + (n1 & 15);
#pragma unroll
    for (int p = 0; p < 4; p++) {
      float2 v = B[base + 16 * p];
      C2 w = TW<SIGN>(tw, 5 * ((p * n1) & 63));
      s.x += v.x * w.x - v.y * w.y;
      s.y += v.x * w.y + v.y * w.x;
    }
    acc = s;
  }
  int o = 5 * n1 + q;
  if (MASKED) {
    float m = misRow[o];
    acc.x *= m; acc.y *= m;
  }
  A[o] = make_float2(acc.x, acc.y);
  __syncthreads();
}

// G(z) = div_x(dx z_re) + div_y(dx z_im)   (reference's channel-0/1 divergence quirk)
DEVFN float Gfunc(const float* __restrict__ z, int b, int h, int w) {
  const float* re = z + b * NC2;
  const float* im = re + NHW;
  int hw = h * NW + w;
  float divx, divy;
  if (w == 0) {
    divx = re[hw + 1] - re[hw];
  } else if (w < NW - 1) {
    divx = (re[hw + 1] - re[hw]) - (re[hw] - re[hw - 1]);
  } else {
    divx = -(re[hw] - re[hw - 1]);
  }
  if (h == 0) {
    divy = (w < NW - 1) ? im[hw + 1] - im[hw] : 0.f;
  } else if (h < NH - 1) {
    float a = (w < NW - 1) ? im[hw + 1] - im[hw] : 0.f;
    float bb = (w < NW - 1) ? im[hw - NW + 1] - im[hw - NW] : 0.f;
    divy = a - bb;
  } else {
    divy = -((w < NW - 1) ? im[hw - NW + 1] - im[hw - NW] : 0.f);
  }
  return divx + divy;
}

// b-term: div_x((u-v)_ch0) + div_y((u-v)_ch1)
DEVFN float divUV(const float* __restrict__ u, const float* __restrict__ v, int b, int h, int w) {
  const float* u0 = u + (b * 4 + 0) * NHW; const float* v0 = v + (b * 4 + 0) * NHW;
  const float* u1 = u + (b * 4 + 1) * NHW; const float* v1 = v + (b * 4 + 1) * NHW;
  int hw = h * NW + w;
  float divx, divy;
  if (w == 0)          divx = u0[hw] - v0[hw];
  else if (w < NW - 1) divx = (u0[hw] - v0[hw]) - (u0[hw - 1] - v0[hw - 1]);
  else                 divx = -(u0[hw - 1] - v0[hw - 1]);
  if (h == 0)          divy = u1[hw] - v1[hw];
  else if (h < NH - 1) divy = (u1[hw] - v1[hw]) - (u1[hw - NW] - v1[hw - NW]);
  else                 divy = -(u1[hw - NW] - v1[hw - NW]);
  return divx + divy;
}

DEVFN double shflxd(double v, int m) {
  union { double d; int i[2]; } a; a.d = v;
  a.i[0] = __shfl_xor(a.i[0], m, 64);
  a.i[1] = __shfl_xor(a.i[1], m, 64);
  return a.d;
}
DEVFN double waveRed(double v) {
#pragma unroll
  for (int m = 32; m; m >>= 1) v += shflxd(v, m);
  return v;
}

// reduce 1280 per-block partials -> scalar, broadcast (deterministic fixed order)
__device__ double redParts(const double* __restrict__ part, double* sdot, int t) {
  double v = part[t] + part[t + 320] + part[t + 640] + part[t + 960];
  v = waveRed(v);
  if ((t & 63) == 0) sdot[t >> 6] = v;
  __syncthreads();
  double s = sdot[0] + sdot[1] + sdot[2] + sdot[3] + sdot[4];
  __syncthreads();
  return s;
}

__device__ void blockDot1(double a, double* sdot, int t, double* outp) {
  a = waveRed(a);
  if ((t & 63) == 0) sdot[t >> 6] = a;
  __syncthreads();
  if (t == 0) *outp = sdot[0] + sdot[1] + sdot[2] + sdot[3] + sdot[4];
  __syncthreads();
}

__device__ void blockDot3(double a, double b, double c, double* sdot, int t,
                          double* o0, double* o1, double* o2, int bid) {
  a = waveRed(a); b = waveRed(b); c = waveRed(c);
  int wv = t >> 6;
  if ((t & 63) == 0) { sdot[wv * 3] = a; sdot[wv * 3 + 1] = b; sdot[wv * 3 + 2] = c; }
  __syncthreads();
  if (t == 0) {
    double s0 = 0, s1 = 0, s2 = 0;
#pragma unroll
    for (int w2 = 0; w2 < 5; w2++) { s0 += sdot[w2 * 3]; s1 += sdot[w2 * 3 + 1]; s2 += sdot[w2 * 3 + 2]; }
    o0[bid] = s0; o1[bid] = s1; o2[bid] = s2;
  }
  __syncthreads();
}

#define FFTK_SHARED                                     \
  __shared__ float2 sA[320];                            \
  __shared__ float2 sB[320];                            \
  __shared__ double sdot[16];                           \
  (void)sdot;                                           \
  const int t = threadIdx.x;                            \
  const int bid = blockIdx.x;

// ---------------- kernels (grid = 1280 x 320 everywhere) ----------------

// twiddle table + transposed shifted/scaled mask misT[b][w][h]
__global__ __launch_bounds__(NTHR) void k_init(const float* __restrict__ mask,
                                               float* __restrict__ misT, float2* __restrict__ tw) {
  int t = threadIdx.x, bid = blockIdx.x;
  if (bid == 0) {
    double ang = -2.0 * 3.14159265358979323846 * (double)t / 320.0;
    tw[t] = make_float2((float)cos(ang), (float)sin(ang));
  }
  int i = bid * NTHR + t;  // exactly NB*NHW
  int b = i / NHW, hw = i % NHW, h = hw / NW, w = hw % NW;
  int hs = (h + 160) % 320, ws = (w + 160) % 320;
  misT[b * NHW + w * NW + h] = mask[b * NHW + hs * NW + ws] * (1.0f / 102400.0f);
}

// rows S*IFFT*S of y -> t1 and of mask*y -> t2
__global__ __launch_bounds__(NTHR) void k0a(const float* __restrict__ y, const float* __restrict__ mask,
                                            float2* __restrict__ t1, float2* __restrict__ t2,
                                            const float2* __restrict__ twg) {
  FFTK_SHARED
  const int gb = bid / NH, gl = bid % NH;
  const int rowBase = gb * NC2 + gl * NW;
  float sgn = (t & 1) ? -1.f : 1.f;
  sA[t] = make_float2(sgn * y[rowBase + t], sgn * y[rowBase + NHW + t]);
  fftp<1, false>(sA, sB, twg, t, nullptr);
  {
    float2 v = sA[t];
    t1[gb * NHW + gl * NW + t] = make_float2(sgn * v.x, sgn * v.y);
  }
  float m = mask[gb * NHW + gl * NW + t];
  sA[t] = make_float2(sgn * m * y[rowBase + t], sgn * m * y[rowBase + NHW + t]);
  fftp<1, false>(sA, sB, twg, t, nullptr);
  {
    float2 v = sA[t];
    t2[gb * NHW + gl * NW + t] = make_float2(sgn * v.x, sgn * v.y);
  }
}

// cols S*IFFT*S (scale 1/320): t1 -> x, t2 -> bdata (planar outputs). Swizzled.
__global__ __launch_bounds__(NTHR) void k0b(const float2* __restrict__ t1, const float2* __restrict__ t2,
                                            float* __restrict__ x, float* __restrict__ bdata,
                                            const float2* __restrict__ twg) {
  FFTK_SHARED
  const int wid = swzcol(bid);
  const int gb = wid / NH, gl = wid % NH;
  float sgn = (t & 1) ? -1.f : 1.f;
  {
    float2 v = t1[gb * NHW + t * NW + gl];
    sA[t] = make_float2(sgn * v.x, sgn * v.y);
  }
  fftp<1, false>(sA, sB, twg, t, nullptr);
  {
    float2 v = sA[t];
    float s = sgn * (1.f / 320.f);
    x[gb * NC2 + t * NW + gl] = v.x * s;
    x[gb * NC2 + NHW + t * NW + gl] = v.y * s;
  }
  {
    float2 v = t2[gb * NHW + t * NW + gl];
    sA[t] = make_float2(sgn * v.x, sgn * v.y);
  }
  fftp<1, false>(sA, sB, twg, t, nullptr);
  {
    float2 v = sA[t];
    float s = sgn * (1.f / 320.f);
    bdata[gb * NC2 + t * NW + gl] = v.x * s;
    bdata[gb * NC2 + NHW + t * NW + gl] = v.y * s;
  }
}

// u = gradient(x), v = 0 (1 site/thread); xc = x; rowFFT(x) -> t1
__global__ __launch_bounds__(NTHR) void ka0(const float* __restrict__ x, float* __restrict__ xc,
                                            float* __restrict__ u, float* __restrict__ v,
                                            float2* __restrict__ t1, const float2* __restrict__ twg) {
  FFTK_SHARED
  const int gb = bid / NH, gl = bid % NH;
  const int rowBase = gb * NC2 + gl * NW;
  {
    int i = bid * NTHR + t;
    int b = i / NHW, hw = i % NHW, h = hw / NW, w = hw % NW;
    const float* re = x + b * NC2;
    const float* im = re + NHW;
    float g0 = (w < NW - 1) ? re[hw + 1] - re[hw] : 0.f;
    float g1 = (w < NW - 1) ? im[hw + 1] - im[hw] : 0.f;
    float g2 = (h < NH - 1) ? re[hw + NW] - re[hw] : 0.f;
    float g3 = (h < NH - 1) ? im[hw + NW] - im[hw] : 0.f;
    int b4 = b * 4 * NHW;
    u[b4 + hw] = g0;           v[b4 + hw] = 0.f;
    u[b4 + NHW + hw] = g1;     v[b4 + NHW + hw] = 0.f;
    u[b4 + 2 * NHW + hw] = g2; v[b4 + 2 * NHW + hw] = 0.f;
    u[b4 + 3 * NHW + hw] = g3; v[b4 + 3 * NHW + hw] = 0.f;
  }
  float re = x[rowBase + t], im = x[rowBase + NHW + t];
  xc[rowBase + t] = re; xc[rowBase + NHW + t] = im;
  sA[t] = make_float2(re, im);
  fftp<-1, false>(sA, sB, twg, t, nullptr);
  t1[gb * NHW + gl * NW + t] = sA[t];
}

// [it>0: reduce prev pres/dres -> hist; guarded u/v commit] ; colFM(t1). Swizzled.
__global__ __launch_bounds__(NTHR) void kb(float2* __restrict__ t1, const float* __restrict__ misT,
                                           const float* __restrict__ un, const float* __restrict__ vn,
                                           float* __restrict__ u, float* __restrict__ v,
                                           const double* __restrict__ pPaPrev, const double* __restrict__ pPbPrev,
                                           double* __restrict__ hist_pres, double* __restrict__ hist_dres,
                                           const float2* __restrict__ twg, int it) {
  FFTK_SHARED
  const int wid = swzcol(bid);
  const int gb = wid / NH, gl = wid % NH;
  if (it > 0) {
    double ppa = redParts(pPaPrev, sdot, t);
    double ppb = redParts(pPbPrev, sdot, t);
    if (bid == 0 && t == 0) { hist_pres[it - 1] = ppa; hist_dres[it - 1] = ppb; }
    // commit guard is done_before(it-1) = OR_{j<=it-2} stop_j
    bool doneA = false;
    for (int j = 0; j <= it - 2; j++) {
      float pr = sqrtf((float)hist_pres[j]), dr = sqrtf((float)hist_dres[j]);
      doneA |= (pr < 1e-4f && dr < 1e-4f);
    }
    if (!doneA) {
      for (int i = wid * NTHR + t; i < NB * 4 * NHW; i += GRID * NTHR) { u[i] = un[i]; v[i] = vn[i]; }
    }
  }
  sA[t] = t1[gb * NHW + t * NW + gl];
  fftp<-1, true>(sA, sB, twg, t, misT + gb * NHW + gl * NW);
  fftp<1, false>(sA, sB, twg, t, nullptr);
  t1[gb * NHW + t * NW + gl] = sA[t];
}

// rowIFFT(t1) -> A(x); r = p = (bdata + divUV) - A(x); rsold partials; rowFFT(p) -> t1
__global__ __launch_bounds__(NTHR) void kcd(float2* __restrict__ t1, const float* __restrict__ x,
                                            const float* __restrict__ u, const float* __restrict__ v,
                                            const float* __restrict__ bdata, float* __restrict__ r,
                                            float* __restrict__ p, double* __restrict__ pRS,
                                            const float2* __restrict__ twg) {
  FFTK_SHARED
  const int gb = bid / NH, gl = bid % NH;
  const int rowBase = gb * NC2 + gl * NW;
  sA[t] = t1[gb * NHW + gl * NW + t];
  fftp<1, false>(sA, sB, twg, t, nullptr);
  float2 Av = sA[t];
  float G = Gfunc(x, gb, gl, t);
  float Ar = Av.x - G, Ai = Av.y - G;
  float d = divUV(u, v, gb, gl, t);
  float br = bdata[rowBase + t] + d;
  float bi = bdata[rowBase + NHW + t] + d;
  float rr = br - Ar, ri = bi - Ai;
  r[rowBase + t] = rr; r[rowBase + NHW + t] = ri;
  p[rowBase + t] = rr; p[rowBase + NHW + t] = ri;
  double acc = (double)rr * rr + (double)ri * ri;
  blockDot1(acc, sdot, t, &pRS[bid]);
  sA[t] = make_float2(rr, ri);
  fftp<-1, false>(sA, sB, twg, t, nullptr);
  t1[gb * NHW + gl * NW + t] = sA[t];
}

// k>=1: reduce dots; update xc, r, p; rowFFT(p) -> t1
__global__ __launch_bounds__(NTHR) void kd(float* __restrict__ xc, float* __restrict__ r,
                                           float* __restrict__ p, const float* __restrict__ Ap,
                                           float2* __restrict__ t1, const double* __restrict__ pRS,
                                           const double* __restrict__ pD0, const double* __restrict__ pD1,
                                           const double* __restrict__ pD2, double* __restrict__ hist_rs,
                                           const float2* __restrict__ twg, int k) {
  FFTK_SHARED
  const int gb = bid / NH, gl = bid % NH;
  const int rowBase = gb * NC2 + gl * NW;
  double pAp = redParts(pD0, sdot, t);
  double rAp = redParts(pD1, sdot, t);
  double A2  = redParts(pD2, sdot, t);
  double rsold = (k == 1) ? redParts(pRS, sdot, t) : hist_rs[k - 2];
  float alpha = (float)rsold / ((float)pAp + 1e-12f);
  // exact algebraic expansion of ||r - alpha*Ap||^2 (no conjugacy assumption)
  double rsnew = rsold - 2.0 * (double)alpha * rAp + (double)alpha * (double)alpha * A2;
  if (bid == 0 && t == 0) hist_rs[k - 1] = rsnew;
  bool doneIn = false;
  for (int j = 0; j <= k - 2; j++) doneIn |= ((float)hist_rs[j] < 1e-10f);
  bool stop = ((float)rsnew < 1e-10f);
  bool doneP = doneIn || stop;
  float beta = (float)rsnew / (float)rsold;
  float pn2[2];
#pragma unroll
  for (int half = 0; half < 2; half++) {
    int a = rowBase + half * NHW + t;
    float pv = p[a], rv = r[a], av = Ap[a], xv = xc[a];
    float rn = rv, xn = xv;
    if (!doneIn) { xn += alpha * pv; rn -= alpha * av; }
    float pn = doneP ? pv : (rn + beta * pv);
    xc[a] = xn; r[a] = rn; p[a] = pn;
    pn2[half] = pn;
  }
  sA[t] = make_float2(pn2[0], pn2[1]);
  fftp<-1, false>(sA, sB, twg, t, nullptr);
  t1[gb * NHW + gl * NW + t] = sA[t];
}

// plain colFM (mask fused into forward FFT tail). Swizzled.
__global__ __launch_bounds__(NTHR) void ke(float2* __restrict__ t1, const float* __restrict__ misT,
                                           const float2* __restrict__ twg) {
  FFTK_SHARED
  const int wid = swzcol(bid);
  const int gb = wid / NH, gl = wid % NH;
  sA[t] = t1[gb * NHW + t * NW + gl];
  fftp<-1, true>(sA, sB, twg, t, misT + gb * NHW + gl * NW);
  fftp<1, false>(sA, sB, twg, t, nullptr);
  t1[gb * NHW + t * NW + gl] = sA[t];
}

// rowIFFT(t1) -> Ap = M(p) - G(p); dots p.Ap, r.Ap, Ap.Ap
__global__ __launch_bounds__(NTHR) void kf(const float2* __restrict__ t1, const float* __restrict__ p,
                                           const float* __restrict__ r, float* __restrict__ Ap,
                                           double* __restrict__ pD0, double* __restrict__ pD1,
                                           double* __restrict__ pD2, const float2* __restrict__ twg) {
  FFTK_SHARED
  const int gb = bid / NH, gl = bid % NH;
  const int rowBase = gb * NC2 + gl * NW;
  sA[t] = t1[gb * NHW + gl * NW + t];
  fftp<1, false>(sA, sB, twg, t, nullptr);
  float2 Av = sA[t];
  float G = Gfunc(p, gb, gl, t);
  float Ar = Av.x - G, Ai = Av.y - G;
  Ap[rowBase + t] = Ar; Ap[rowBase + NHW + t] = Ai;
  float pr = p[rowBase + t], pi = p[rowBase + NHW + t];
  float rr = r[rowBase + t], ri = r[rowBase + NHW + t];
  double aP = (double)pr * Ar + (double)pi * Ai;
  double aR = (double)rr * Ar + (double)ri * Ai;
  double aA = (double)Ar * Ar + (double)Ai * Ai;
  blockDot3(aP, aR, aA, sdot, t, pD0, pD1, pD2, bid);
}

// final CG x-update; xn -> t1 (spatial, interleaved); un/vn; pres partials. 1 site/thread.
__global__ __launch_bounds__(NTHR) void kh1(const float* __restrict__ xc, const float* __restrict__ p,
                                            const float* __restrict__ v, float2* __restrict__ t1,
                                            float* __restrict__ un, float* __restrict__ vn,
                                            const double* __restrict__ pD0, const double* __restrict__ hist_rs,
                                            double* __restrict__ pPaCur) {
  __shared__ double sdot[16];
  const int t = threadIdx.x, bid = blockIdx.x;
  double pAp = redParts(pD0, sdot, t);
  double rsold = hist_rs[8];
  float alphaF = (float)rsold / ((float)pAp + 1e-12f);
  bool doneX = false;
  for (int j = 0; j <= 8; j++) doneX |= ((float)hist_rs[j] < 1e-10f);
  int i = bid * NTHR + t;
  int b = i / NHW, hw = i % NHW, h = hw / NW, w = hw % NW;
  int base = b * NC2;
  auto XN = [&](int off) {
    float vv = xc[base + off];
    if (!doneX) vv += alphaF * p[base + off];
    return vv;
  };
  float xre = XN(hw), xim = XN(NHW + hw);
  float g0 = 0, g1 = 0, g2 = 0, g3 = 0;
  if (w < NW - 1) { g0 = XN(hw + 1) - xre; g1 = XN(NHW + hw + 1) - xim; }
  if (h < NH - 1) { g2 = XN(hw + NW) - xre; g3 = XN(NHW + hw + NW) - xim; }
  t1[b * NHW + hw] = make_float2(xre, xim);
  float gs[4] = {g0, g1, g2, g3};
  double acc = 0.0;
#pragma unroll
  for (int ch = 0; ch < 4; ch++) {
    int ui = (b * 4 + ch) * NHW + hw;
    float vv = v[ui];
    float sv = gs[ch] + vv;
    float a2 = fabsf(sv) - THRESHc;
    float uo = (a2 > 0.f) ? copysignf(a2, sv) : 0.f;
    un[ui] = uo;
    vn[ui] = vv + gs[ch] - uo;
    float dd = gs[ch] - uo;
    acc += (double)dd * dd;
  }
  blockDot1(acc, sdot, t, &pPaCur[bid]);
}

// dres partials (1 site/thread); guarded x commit from t1(xn); xc = x; rowFFT(x) -> t1
__global__ __launch_bounds__(NTHR) void kh2a(float* __restrict__ x, float* __restrict__ xc,
                                             float2* __restrict__ t1, const float* __restrict__ un,
                                             const float* __restrict__ u,
                                             const double* __restrict__ hist_pres,
                                             const double* __restrict__ hist_dres,
                                             double* __restrict__ pPbCur,
                                             const float2* __restrict__ twg, int it) {
  FFTK_SHARED
  const int gb = bid / NH, gl = bid % NH;
  const int rowBase = gb * NC2 + gl * NW;
  // done_before(it) = OR_{j<=it-1} stop_j  (hist[it-1] written by kb(it) this iter)
  bool doneA = false;
  for (int j = 0; j <= it - 1; j++) {
    float pr = sqrtf((float)hist_pres[j]), dr = sqrtf((float)hist_dres[j]);
    doneA |= (pr < 1e-4f && dr < 1e-4f);
  }
  {
    int i = bid * NTHR + t;
    int b = i / NHW, hw = i % NHW, h = hw / NW, w = hw % NW;
    const float* N0 = un + (b * 4 + 0) * NHW; const float* U0 = u + (b * 4 + 0) * NHW;
    const float* N1 = un + (b * 4 + 1) * NHW; const float* U1 = u + (b * 4 + 1) * NHW;
    float divx, divy;
    if (w == 0)          divx = N0[hw] - U0[hw];
    else if (w < NW - 1) divx = (N0[hw] - U0[hw]) - (N0[hw - 1] - U0[hw - 1]);
    else                 divx = -(N0[hw - 1] - U0[hw - 1]);
    if (h == 0)          divy = N1[hw] - U1[hw];
    else if (h < NH - 1) divy = (N1[hw] - U1[hw]) - (N1[hw - NW] - U1[hw - NW]);
    else                 divy = -(N1[hw - NW] - U1[hw - NW]);
    float d = divx + divy;
    double acc = (double)d * d;
    blockDot1(acc, sdot, t, &pPbCur[bid]);
  }
  float2 xn = t1[gb * NHW + gl * NW + t];
  float xfr, xfi;
  if (doneA) { xfr = x[rowBase + t]; xfi = x[rowBase + NHW + t]; }
  else       { xfr = xn.x; xfi = xn.y; }
  x[rowBase + t] = xfr; x[rowBase + NHW + t] = xfi;
  xc[rowBase + t] = xfr; xc[rowBase + NHW + t] = xfi;
  sA[t] = make_float2(xfr, xfi);
  fftp<-1, false>(sA, sB, twg, t, nullptr);
  t1[gb * NHW + gl * NW + t] = sA[t];
}

__global__ __launch_bounds__(NTHR) void k_out(const float* __restrict__ x,
                                              const double* __restrict__ hist_pres,
                                              const double* __restrict__ hist_dres,
                                              const double* __restrict__ pPa9,
                                              const double* __restrict__ pPb9,
                                              float* __restrict__ out) {
  __shared__ double sdot[16];
  const int t = threadIdx.x, bid = blockIdx.x;
  for (int i = bid * NTHR + t; i < NB * NC2; i += GRID * NTHR) out[i] = x[i];
  if (bid == 0) {
    double p9 = redParts(pPa9, sdot, t);
    double d9 = redParts(pPb9, sdot, t);
    if (t == 0) {
      int count = 0; bool done = false; float presO = 0.f, dresO = 0.f;
      for (int it = 0; it < 10; ++it) {
        double hp = (it == 9) ? p9 : hist_pres[it];
        double hd = (it == 9) ? d9 : hist_dres[it];
        if (!done) {
          count++;
          presO = sqrtf((float)hp);
          dresO = sqrtf((float)hd);
          done = (presO < 1e-4f) && (dresO < 1e-4f);
        }
      }
      out[NB * NC2 + 0] = (float)count;
      out[NB * NC2 + 1] = presO;
      out[NB * NC2 + 2] = dresO;
    }
  }
}

}  // namespace

extern "C" void kernel_launch(void* const* d_in, const int* in_sizes, int n_in,
                              void* d_out, int out_size, void* d_ws, size_t ws_size,
                              hipStream_t stream) {
  (void)in_sizes; (void)n_in; (void)out_size; (void)ws_size;
  const float* y = (const float*)d_in[0];
  const float* mask = (const float*)d_in[1];
  float* out = (float*)d_out;
  float* wsf = (float*)d_ws;

  double* dws = (double*)wsf;
  double* pRS       = dws;           // 1280
  double* pD0       = dws + 1280;
  double* pD1       = dws + 2560;
  double* pD2       = dws + 3840;
  double* pPa       = dws + 5120;    // 2 x 1280 (parity)
  double* pPb       = dws + 7680;    // 2 x 1280 (parity)
  double* hist_rs   = dws + 10240;   // 16
  double* hist_pres = dws + 10256;   // 16
  double* hist_dres = dws + 10272;   // 16 -> ends at 10288 doubles

  float* fb = wsf + 20576;           // after 10288 doubles
  float2* tw = (float2*)fb; fb += 640;
  float* misT = fb; fb += (size_t)NB * NHW;
  float2* t1 = (float2*)fb; fb += (size_t)2 * NB * NHW;
  float2* t2 = (float2*)fb; fb += (size_t)2 * NB * NHW;
  auto take = [&](size_t n) { float* ptr = fb; fb += n; return ptr; };
  float* x     = take((size_t)NB * NC2);
  float* xc    = take((size_t)NB * NC2);
  float* r     = take((size_t)NB * NC2);
  float* p     = take((size_t)NB * NC2);
  float* Ap    = take((size_t)NB * NC2);
  float* bdata = take((size_t)NB * NC2);
  float* u     = take((size_t)NB * 4 * NHW);
  float* v     = take((size_t)NB * 4 * NHW);
  float* un    = take((size_t)NB * 4 * NHW);
  float* vn    = take((size_t)NB * 4 * NHW);

  k_init<<<GRID, NTHR, 0, stream>>>(mask, misT, tw);
  k0a<<<GRID, NTHR, 0, stream>>>(y, mask, t1, t2, tw);
  k0b<<<GRID, NTHR, 0, stream>>>(t1, t2, x, bdata, tw);
  ka0<<<GRID, NTHR, 0, stream>>>(x, xc, u, v, t1, tw);

  for (int it = 0; it < 10; ++it) {
    int prevPar = (it + 1) & 1;  // (it-1)&1
    int curPar = it & 1;
    kb<<<GRID, NTHR, 0, stream>>>(t1, misT, un, vn, u, v,
                                  pPa + prevPar * 1280, pPb + prevPar * 1280,
                                  hist_pres, hist_dres, tw, it);
    kcd<<<GRID, NTHR, 0, stream>>>(t1, x, u, v, bdata, r, p, pRS, tw);
    ke<<<GRID, NTHR, 0, stream>>>(t1, misT, tw);
    kf<<<GRID, NTHR, 0, stream>>>(t1, p, r, Ap, pD0, pD1, pD2, tw);
    for (int k = 1; k < 10; ++k) {
      kd<<<GRID, NTHR, 0, stream>>>(xc, r, p, Ap, t1, pRS, pD0, pD1, pD2, hist_rs, tw, k);
      ke<<<GRID, NTHR, 0, stream>>>(t1, misT, tw);
      kf<<<GRID, NTHR, 0, stream>>>(t1, p, r, Ap, pD0, pD1, pD2, tw);
    }
    kh1<<<GRID, NTHR, 0, stream>>>(xc, p, v, t1, un, vn, pD0, hist_rs, pPa + curPar * 1280);
    kh2a<<<GRID, NTHR, 0, stream>>>(x, xc, t1, un, u, hist_pres, hist_dres,
                                    pPb + curPar * 1280, tw, it);
  }
  k_out<<<GRID, NTHR, 0, stream>>>(x, hist_pres, hist_dres, pPa + 1280, pPb + 1280, out);
}

// Round 6
// 2997.612 us; speedup vs baseline: 1.5045x; 1.5045x over previous
//
#include <hip/hip_runtime.h>
#include <math.h>

#define DEVFN __device__ __forceinline__

namespace {

constexpr int NW = 320, NH = 320, NHW = NW * NH, NB = 4;
constexpr int NC2 = 2 * NHW;          // floats per complex image (planar re/im)
constexpr int GRID = NB * NH;         // 1280 blocks (one line per block)
constexpr int NTHR = 320;             // one point per thread
constexpr float THRESHc = 0.01f;      // LAMBDA_TV / RHO

struct C2 { float x, y; };
DEVFN C2 cmul(C2 a, C2 b) { return C2{a.x * b.x - a.y * b.y, a.x * b.y + a.y * b.x}; }

template <int SIGN>
DEVFN C2 TW(const float2* tw, int m) {
  float2 t = tw[m];
  return C2{t.x, (SIGN < 0) ? t.y : -t.y};
}

// XCD-chunked swizzle for column kernels: adjacent columns -> same XCD L2
DEVFN int swzcol(int bid) { return (bid & 7) * (GRID / 8) + (bid >> 3); }

// 320-pt FFT, 320 threads (1 point each), mixed radix 5*4*4*4.
// Input: A natural order (caller fills sA[t], fftp starts with sync).
// Output: A natural order (trailing sync included). tw = LDS copy of cis(-2*pi*m/320).
// MASKED: multiply final-stage register value by misRow[5*n1+q] before store.
template <int SIGN, bool MASKED>
__device__ void fftp(float2* A, float2* B, const float2* tw, int t,
                     const float* __restrict__ misRow) {
  const int q = t >> 6, n1 = t & 63;
  __syncthreads();  // A (and staged tw) ready
  C2 acc;
  {  // radix-5 over stride-64 + twiddle w320^{n1 q}
    float2 v0 = A[n1];
    acc.x = v0.x; acc.y = v0.y;
#pragma unroll
    for (int n2 = 1; n2 < 5; n2++) {
      float2 v = A[n1 + 64 * n2];
      C2 w = TW<SIGN>(tw, 64 * ((n2 * q) % 5));
      acc.x += v.x * w.x - v.y * w.y;
      acc.y += v.x * w.y + v.y * w.x;
    }
    acc = cmul(acc, TW<SIGN>(tw, n1 * q));  // n1*q <= 252 < 320
  }
  B[t] = make_float2(acc.x, acc.y);
  __syncthreads();
  {  // radix-4, Lr=4 (w4 = tw[80*..])
    C2 s{0.f, 0.f};
    int rr = n1 & 3, base = (q << 6) + (n1 >> 2);
#pragma unroll
    for (int p = 0; p < 4; p++) {
      float2 v = B[base + 16 * p];
      C2 w = TW<SIGN>(tw, 80 * ((p * rr) & 3));
      s.x += v.x * w.x - v.y * w.y;
      s.y += v.x * w.y + v.y * w.x;
    }
    acc = s;
  }
  A[t] = make_float2(acc.x, acc.y);
  __syncthreads();
  {  // radix-4, Lr=16 (w16 = tw[20*..])
    C2 s{0.f, 0.f};
    int rr = n1 & 15, base = (q << 6) + ((n1 >> 4) << 2) + (n1 & 3);
#pragma unroll
    for (int p = 0; p < 4; p++) {
      float2 v = A[base + 16 * p];
      C2 w = TW<SIGN>(tw, 20 * ((p * rr) & 15));
      s.x += v.x * w.x - v.y * w.y;
      s.y += v.x * w.y + v.y * w.x;
    }
    acc = s;
  }
  B[t] = make_float2(acc.x, acc.y);
  __syncthreads();
  {  // radix-4, Lr=64 (w64 = tw[5*..]) -> output index 5*n1+q
    C2 s{0.f, 0.f};
    int base = (q << 6) + (n1 & 15);
#pragma unroll
    for (int p = 0; p < 4; p++) {
      float2 v = B[base + 16 * p];
      C2 w = TW<SIGN>(tw, 5 * ((p * n1) & 63));
      s.x += v.x * w.x - v.y * w.y;
      s.y += v.x * w.y + v.y * w.x;
    }
    acc = s;
  }
  int o = 5 * n1 + q;
  if (MASKED) {
    float m = misRow[o];
    acc.x *= m; acc.y *= m;
  }
  A[o] = make_float2(acc.x, acc.y);
  __syncthreads();
}

// G(z) = div_x(dx z_re) + div_y(dx z_im)   (reference's channel-0/1 divergence quirk)
DEVFN float Gfunc(const float* __restrict__ z, int b, int h, int w) {
  const float* re = z + b * NC2;
  const float* im = re + NHW;
  int hw = h * NW + w;
  float divx, divy;
  if (w == 0) {
    divx = re[hw + 1] - re[hw];
  } else if (w < NW - 1) {
    divx = (re[hw + 1] - re[hw]) - (re[hw] - re[hw - 1]);
  } else {
    divx = -(re[hw] - re[hw - 1]);
  }
  if (h == 0) {
    divy = (w < NW - 1) ? im[hw + 1] - im[hw] : 0.f;
  } else if (h < NH - 1) {
    float a = (w < NW - 1) ? im[hw + 1] - im[hw] : 0.f;
    float bb = (w < NW - 1) ? im[hw - NW + 1] - im[hw - NW] : 0.f;
    divy = a - bb;
  } else {
    divy = -((w < NW - 1) ? im[hw - NW + 1] - im[hw - NW] : 0.f);
  }
  return divx + divy;
}

// b-term: div_x((u-v)_ch0) + div_y((u-v)_ch1)
DEVFN float divUV(const float* __restrict__ u, const float* __restrict__ v, int b, int h, int w) {
  const float* u0 = u + (b * 4 + 0) * NHW; const float* v0 = v + (b * 4 + 0) * NHW;
  const float* u1 = u + (b * 4 + 1) * NHW; const float* v1 = v + (b * 4 + 1) * NHW;
  int hw = h * NW + w;
  float divx, divy;
  if (w == 0)          divx = u0[hw] - v0[hw];
  else if (w < NW - 1) divx = (u0[hw] - v0[hw]) - (u0[hw - 1] - v0[hw - 1]);
  else                 divx = -(u0[hw - 1] - v0[hw - 1]);
  if (h == 0)          divy = u1[hw] - v1[hw];
  else if (h < NH - 1) divy = (u1[hw] - v1[hw]) - (u1[hw - NW] - v1[hw - NW]);
  else                 divy = -(u1[hw - NW] - v1[hw - NW]);
  return divx + divy;
}

DEVFN double shflxd(double v, int m) {
  union { double d; int i[2]; } a; a.d = v;
  a.i[0] = __shfl_xor(a.i[0], m, 64);
  a.i[1] = __shfl_xor(a.i[1], m, 64);
  return a.d;
}
DEVFN double waveRed(double v) {
#pragma unroll
  for (int m = 32; m; m >>= 1) v += shflxd(v, m);
  return v;
}

// reduce 1280 per-block partials -> scalar, broadcast (deterministic fixed order)
__device__ double redParts(const double* __restrict__ part, double* sdot, int t) {
  double v = part[t] + part[t + 320] + part[t + 640] + part[t + 960];
  v = waveRed(v);
  if ((t & 63) == 0) sdot[t >> 6] = v;
  __syncthreads();
  double s = sdot[0] + sdot[1] + sdot[2] + sdot[3] + sdot[4];
  __syncthreads();
  return s;
}

__device__ void blockDot1(double a, double* sdot, int t, double* outp) {
  a = waveRed(a);
  if ((t & 63) == 0) sdot[t >> 6] = a;
  __syncthreads();
  if (t == 0) *outp = sdot[0] + sdot[1] + sdot[2] + sdot[3] + sdot[4];
  __syncthreads();
}

__device__ void blockDot3(double a, double b, double c, double* sdot, int t,
                          double* o0, double* o1, double* o2, int bid) {
  a = waveRed(a); b = waveRed(b); c = waveRed(c);
  int wv = t >> 6;
  if ((t & 63) == 0) { sdot[wv * 3] = a; sdot[wv * 3 + 1] = b; sdot[wv * 3 + 2] = c; }
  __syncthreads();
  if (t == 0) {
    double s0 = 0, s1 = 0, s2 = 0;
#pragma unroll
    for (int w2 = 0; w2 < 5; w2++) { s0 += sdot[w2 * 3]; s1 += sdot[w2 * 3 + 1]; s2 += sdot[w2 * 3 + 2]; }
    o0[bid] = s0; o1[bid] = s1; o2[bid] = s2;
  }
  __syncthreads();
}

#define FFTK_SHARED                                     \
  __shared__ float2 sA[320];                            \
  __shared__ float2 sB[320];                            \
  __shared__ float2 stw[320];                           \
  __shared__ double sdot[16];                           \
  (void)sdot;                                           \
  const int t = threadIdx.x;                            \
  const int bid = blockIdx.x;                           \
  stw[t] = twg[t];

// ---------------- kernels (grid = 1280 x 320 everywhere) ----------------

// twiddle table + transposed shifted/scaled mask misT[b][w][h]
__global__ __launch_bounds__(NTHR) void k_init(const float* __restrict__ mask,
                                               float* __restrict__ misT, float2* __restrict__ tw) {
  int t = threadIdx.x, bid = blockIdx.x;
  if (bid == 0) {
    double ang = -2.0 * 3.14159265358979323846 * (double)t / 320.0;
    tw[t] = make_float2((float)cos(ang), (float)sin(ang));
  }
  int i = bid * NTHR + t;  // exactly NB*NHW
  int b = i / NHW, hw = i % NHW, h = hw / NW, w = hw % NW;
  int hs = (h + 160) % 320, ws = (w + 160) % 320;
  misT[b * NHW + w * NW + h] = mask[b * NHW + hs * NW + ws] * (1.0f / 102400.0f);
}

// rows S*IFFT*S of y -> t1 and of mask*y -> t2
__global__ __launch_bounds__(NTHR) void k0a(const float* __restrict__ y, const float* __restrict__ mask,
                                            float2* __restrict__ t1, float2* __restrict__ t2,
                                            const float2* __restrict__ twg) {
  FFTK_SHARED
  const int gb = bid / NH, gl = bid % NH;
  const int rowBase = gb * NC2 + gl * NW;
  float sgn = (t & 1) ? -1.f : 1.f;
  sA[t] = make_float2(sgn * y[rowBase + t], sgn * y[rowBase + NHW + t]);
  fftp<1, false>(sA, sB, stw, t, nullptr);
  {
    float2 v = sA[t];
    t1[gb * NHW + gl * NW + t] = make_float2(sgn * v.x, sgn * v.y);
  }
  float m = mask[gb * NHW + gl * NW + t];
  sA[t] = make_float2(sgn * m * y[rowBase + t], sgn * m * y[rowBase + NHW + t]);
  fftp<1, false>(sA, sB, stw, t, nullptr);
  {
    float2 v = sA[t];
    t2[gb * NHW + gl * NW + t] = make_float2(sgn * v.x, sgn * v.y);
  }
}

// cols S*IFFT*S (scale 1/320): t1 -> x, t2 -> bdata (planar outputs). Swizzled.
__global__ __launch_bounds__(NTHR) void k0b(const float2* __restrict__ t1, const float2* __restrict__ t2,
                                            float* __restrict__ x, float* __restrict__ bdata,
                                            const float2* __restrict__ twg) {
  FFTK_SHARED
  const int wid = swzcol(bid);
  const int gb = wid / NH, gl = wid % NH;
  float sgn = (t & 1) ? -1.f : 1.f;
  {
    float2 v = t1[gb * NHW + t * NW + gl];
    sA[t] = make_float2(sgn * v.x, sgn * v.y);
  }
  fftp<1, false>(sA, sB, stw, t, nullptr);
  {
    float2 v = sA[t];
    float s = sgn * (1.f / 320.f);
    x[gb * NC2 + t * NW + gl] = v.x * s;
    x[gb * NC2 + NHW + t * NW + gl] = v.y * s;
  }
  {
    float2 v = t2[gb * NHW + t * NW + gl];
    sA[t] = make_float2(sgn * v.x, sgn * v.y);
  }
  fftp<1, false>(sA, sB, stw, t, nullptr);
  {
    float2 v = sA[t];
    float s = sgn * (1.f / 320.f);
    bdata[gb * NC2 + t * NW + gl] = v.x * s;
    bdata[gb * NC2 + NHW + t * NW + gl] = v.y * s;
  }
}

// u = gradient(x), v = 0 (1 site/thread); xc = x; rowFFT(x) -> t1
__global__ __launch_bounds__(NTHR) void ka0(const float* __restrict__ x, float* __restrict__ xc,
                                            float* __restrict__ u, float* __restrict__ v,
                                            float2* __restrict__ t1, const float2* __restrict__ twg) {
  FFTK_SHARED
  const int gb = bid / NH, gl = bid % NH;
  const int rowBase = gb * NC2 + gl * NW;
  {
    int i = bid * NTHR + t;
    int b = i / NHW, hw = i % NHW, h = hw / NW, w = hw % NW;
    const float* re = x + b * NC2;
    const float* im = re + NHW;
    float g0 = (w < NW - 1) ? re[hw + 1] - re[hw] : 0.f;
    float g1 = (w < NW - 1) ? im[hw + 1] - im[hw] : 0.f;
    float g2 = (h < NH - 1) ? re[hw + NW] - re[hw] : 0.f;
    float g3 = (h < NH - 1) ? im[hw + NW] - im[hw] : 0.f;
    int b4 = b * 4 * NHW;
    u[b4 + hw] = g0;           v[b4 + hw] = 0.f;
    u[b4 + NHW + hw] = g1;     v[b4 + NHW + hw] = 0.f;
    u[b4 + 2 * NHW + hw] = g2; v[b4 + 2 * NHW + hw] = 0.f;
    u[b4 + 3 * NHW + hw] = g3; v[b4 + 3 * NHW + hw] = 0.f;
  }
  float re = x[rowBase + t], im = x[rowBase + NHW + t];
  xc[rowBase + t] = re; xc[rowBase + NHW + t] = im;
  sA[t] = make_float2(re, im);
  fftp<-1, false>(sA, sB, stw, t, nullptr);
  t1[gb * NHW + gl * NW + t] = sA[t];
}

// [it>0: reduce prev pres/dres -> hist; guarded u/v commit] ; colFM(t1). Swizzled.
__global__ __launch_bounds__(NTHR) void kb(float2* __restrict__ t1, const float* __restrict__ misT,
                                           const float* __restrict__ un, const float* __restrict__ vn,
                                           float* __restrict__ u, float* __restrict__ v,
                                           const double* __restrict__ pPaPrev, const double* __restrict__ pPbPrev,
                                           double* __restrict__ hist_pres, double* __restrict__ hist_dres,
                                           const float2* __restrict__ twg, int it) {
  FFTK_SHARED
  const int wid = swzcol(bid);
  const int gb = wid / NH, gl = wid % NH;
  if (it > 0) {
    double ppa = redParts(pPaPrev, sdot, t);
    double ppb = redParts(pPbPrev, sdot, t);
    if (bid == 0 && t == 0) { hist_pres[it - 1] = ppa; hist_dres[it - 1] = ppb; }
    // commit guard is done_before(it-1) = OR_{j<=it-2} stop_j
    bool doneA = false;
    for (int j = 0; j <= it - 2; j++) {
      float pr = sqrtf((float)hist_pres[j]), dr = sqrtf((float)hist_dres[j]);
      doneA |= (pr < 1e-4f && dr < 1e-4f);
    }
    if (!doneA) {
      for (int i = wid * NTHR + t; i < NB * 4 * NHW; i += GRID * NTHR) { u[i] = un[i]; v[i] = vn[i]; }
    }
  }
  sA[t] = t1[gb * NHW + t * NW + gl];
  fftp<-1, true>(sA, sB, stw, t, misT + gb * NHW + gl * NW);
  fftp<1, false>(sA, sB, stw, t, nullptr);
  t1[gb * NHW + t * NW + gl] = sA[t];
}

// rowIFFT(t1) -> A(x); r = p = (bdata + divUV) - A(x); rsold partials; rowFFT(p) -> t1
__global__ __launch_bounds__(NTHR) void kcd(float2* __restrict__ t1, const float* __restrict__ x,
                                            const float* __restrict__ u, const float* __restrict__ v,
                                            const float* __restrict__ bdata, float* __restrict__ r,
                                            float* __restrict__ p, double* __restrict__ pRS,
                                            const float2* __restrict__ twg) {
  FFTK_SHARED
  const int gb = bid / NH, gl = bid % NH;
  const int rowBase = gb * NC2 + gl * NW;
  sA[t] = t1[gb * NHW + gl * NW + t];
  fftp<1, false>(sA, sB, stw, t, nullptr);
  float2 Av = sA[t];
  float G = Gfunc(x, gb, gl, t);
  float Ar = Av.x - G, Ai = Av.y - G;
  float d = divUV(u, v, gb, gl, t);
  float br = bdata[rowBase + t] + d;
  float bi = bdata[rowBase + NHW + t] + d;
  float rr = br - Ar, ri = bi - Ai;
  r[rowBase + t] = rr; r[rowBase + NHW + t] = ri;
  p[rowBase + t] = rr; p[rowBase + NHW + t] = ri;
  double acc = (double)rr * rr + (double)ri * ri;
  blockDot1(acc, sdot, t, &pRS[bid]);
  sA[t] = make_float2(rr, ri);
  fftp<-1, false>(sA, sB, stw, t, nullptr);
  t1[gb * NHW + gl * NW + t] = sA[t];
}

// k>=1: reduce dots; update xc, r, p; rowFFT(p) -> t1
__global__ __launch_bounds__(NTHR) void kd(float* __restrict__ xc, float* __restrict__ r,
                                           float* __restrict__ p, const float* __restrict__ Ap,
                                           float2* __restrict__ t1, const double* __restrict__ pRS,
                                           const double* __restrict__ pD0, const double* __restrict__ pD1,
                                           const double* __restrict__ pD2, double* __restrict__ hist_rs,
                                           const float2* __restrict__ twg, int k) {
  FFTK_SHARED
  const int gb = bid / NH, gl = bid % NH;
  const int rowBase = gb * NC2 + gl * NW;
  double pAp = redParts(pD0, sdot, t);
  double rAp = redParts(pD1, sdot, t);
  double A2  = redParts(pD2, sdot, t);
  double rsold = (k == 1) ? redParts(pRS, sdot, t) : hist_rs[k - 2];
  float alpha = (float)rsold / ((float)pAp + 1e-12f);
  // exact algebraic expansion of ||r - alpha*Ap||^2 (no conjugacy assumption)
  double rsnew = rsold - 2.0 * (double)alpha * rAp + (double)alpha * (double)alpha * A2;
  if (bid == 0 && t == 0) hist_rs[k - 1] = rsnew;
  bool doneIn = false;
  for (int j = 0; j <= k - 2; j++) doneIn |= ((float)hist_rs[j] < 1e-10f);
  bool stop = ((float)rsnew < 1e-10f);
  bool doneP = doneIn || stop;
  float beta = (float)rsnew / (float)rsold;
  float pn2[2];
#pragma unroll
  for (int half = 0; half < 2; half++) {
    int a = rowBase + half * NHW + t;
    float pv = p[a], rv = r[a], av = Ap[a], xv = xc[a];
    float rn = rv, xn = xv;
    if (!doneIn) { xn += alpha * pv; rn -= alpha * av; }
    float pn = doneP ? pv : (rn + beta * pv);
    xc[a] = xn; r[a] = rn; p[a] = pn;
    pn2[half] = pn;
  }
  sA[t] = make_float2(pn2[0], pn2[1]);
  fftp<-1, false>(sA, sB, stw, t, nullptr);
  t1[gb * NHW + gl * NW + t] = sA[t];
}

// plain colFM (mask fused into forward FFT tail). Swizzled.
__global__ __launch_bounds__(NTHR) void ke(float2* __restrict__ t1, const float* __restrict__ misT,
                                           const float2* __restrict__ twg) {
  FFTK_SHARED
  const int wid = swzcol(bid);
  const int gb = wid / NH, gl = wid % NH;
  sA[t] = t1[gb * NHW + t * NW + gl];
  fftp<-1, true>(sA, sB, stw, t, misT + gb * NHW + gl * NW);
  fftp<1, false>(sA, sB, stw, t, nullptr);
  t1[gb * NHW + t * NW + gl] = sA[t];
}

// rowIFFT(t1) -> Ap = M(p) - G(p); dots p.Ap, r.Ap, Ap.Ap
__global__ __launch_bounds__(NTHR) void kf(const float2* __restrict__ t1, const float* __restrict__ p,
                                           const float* __restrict__ r, float* __restrict__ Ap,
                                           double* __restrict__ pD0, double* __restrict__ pD1,
                                           double* __restrict__ pD2, const float2* __restrict__ twg) {
  FFTK_SHARED
  const int gb = bid / NH, gl = bid % NH;
  const int rowBase = gb * NC2 + gl * NW;
  sA[t] = t1[gb * NHW + gl * NW + t];
  fftp<1, false>(sA, sB, stw, t, nullptr);
  float2 Av = sA[t];
  float G = Gfunc(p, gb, gl, t);
  float Ar = Av.x - G, Ai = Av.y - G;
  Ap[rowBase + t] = Ar; Ap[rowBase + NHW + t] = Ai;
  float pr = p[rowBase + t], pi = p[rowBase + NHW + t];
  float rr = r[rowBase + t], ri = r[rowBase + NHW + t];
  double aP = (double)pr * Ar + (double)pi * Ai;
  double aR = (double)rr * Ar + (double)ri * Ai;
  double aA = (double)Ar * Ar + (double)Ai * Ai;
  blockDot3(aP, aR, aA, sdot, t, pD0, pD1, pD2, bid);
}

// final CG x-update; xn -> t1 (spatial, interleaved); un/vn; pres partials. 1 site/thread.
__global__ __launch_bounds__(NTHR) void kh1(const float* __restrict__ xc, const float* __restrict__ p,
                                            const float* __restrict__ v, float2* __restrict__ t1,
                                            float* __restrict__ un, float* __restrict__ vn,
                                            const double* __restrict__ pD0, const double* __restrict__ hist_rs,
                                            double* __restrict__ pPaCur) {
  __shared__ double sdot[16];
  const int t = threadIdx.x, bid = blockIdx.x;
  double pAp = redParts(pD0, sdot, t);
  double rsold = hist_rs[8];
  float alphaF = (float)rsold / ((float)pAp + 1e-12f);
  bool doneX = false;
  for (int j = 0; j <= 8; j++) doneX |= ((float)hist_rs[j] < 1e-10f);
  int i = bid * NTHR + t;
  int b = i / NHW, hw = i % NHW, h = hw / NW, w = hw % NW;
  int base = b * NC2;
  auto XN = [&](int off) {
    float vv = xc[base + off];
    if (!doneX) vv += alphaF * p[base + off];
    return vv;
  };
  float xre = XN(hw), xim = XN(NHW + hw);
  float g0 = 0, g1 = 0, g2 = 0, g3 = 0;
  if (w < NW - 1) { g0 = XN(hw + 1) - xre; g1 = XN(NHW + hw + 1) - xim; }
  if (h < NH - 1) { g2 = XN(hw + NW) - xre; g3 = XN(NHW + hw + NW) - xim; }
  t1[b * NHW + hw] = make_float2(xre, xim);
  float gs[4] = {g0, g1, g2, g3};
  double acc = 0.0;
#pragma unroll
  for (int ch = 0; ch < 4; ch++) {
    int ui = (b * 4 + ch) * NHW + hw;
    float vv = v[ui];
    float sv = gs[ch] + vv;
    float a2 = fabsf(sv) - THRESHc;
    float uo = (a2 > 0.f) ? copysignf(a2, sv) : 0.f;
    un[ui] = uo;
    vn[ui] = vv + gs[ch] - uo;
    float dd = gs[ch] - uo;
    acc += (double)dd * dd;
  }
  blockDot1(acc, sdot, t, &pPaCur[bid]);
}

// dres partials (1 site/thread); guarded x commit from t1(xn); xc = x; rowFFT(x) -> t1
__global__ __launch_bounds__(NTHR) void kh2a(float* __restrict__ x, float* __restrict__ xc,
                                             float2* __restrict__ t1, const float* __restrict__ un,
                                             const float* __restrict__ u,
                                             const double* __restrict__ hist_pres,
                                             const double* __restrict__ hist_dres,
                                             double* __restrict__ pPbCur,
                                             const float2* __restrict__ twg, int it) {
  FFTK_SHARED
  const int gb = bid / NH, gl = bid % NH;
  const int rowBase = gb * NC2 + gl * NW;
  // done_before(it) = OR_{j<=it-1} stop_j  (hist[it-1] written by kb(it) this iter)
  bool doneA = false;
  for (int j = 0; j <= it - 1; j++) {
    float pr = sqrtf((float)hist_pres[j]), dr = sqrtf((float)hist_dres[j]);
    doneA |= (pr < 1e-4f && dr < 1e-4f);
  }
  {
    int i = bid * NTHR + t;
    int b = i / NHW, hw = i % NHW, h = hw / NW, w = hw % NW;
    const float* N0 = un + (b * 4 + 0) * NHW; const float* U0 = u + (b * 4 + 0) * NHW;
    const float* N1 = un + (b * 4 + 1) * NHW; const float* U1 = u + (b * 4 + 1) * NHW;
    float divx, divy;
    if (w == 0)          divx = N0[hw] - U0[hw];
    else if (w < NW - 1) divx = (N0[hw] - U0[hw]) - (N0[hw - 1] - U0[hw - 1]);
    else                 divx = -(N0[hw - 1] - U0[hw - 1]);
    if (h == 0)          divy = N1[hw] - U1[hw];
    else if (h < NH - 1) divy = (N1[hw] - U1[hw]) - (N1[hw - NW] - U1[hw - NW]);
    else                 divy = -(N1[hw - NW] - U1[hw - NW]);
    float d = divx + divy;
    double acc = (double)d * d;
    blockDot1(acc, sdot, t, &pPbCur[bid]);
  }
  float2 xn = t1[gb * NHW + gl * NW + t];
  float xfr, xfi;
  if (doneA) { xfr = x[rowBase + t]; xfi = x[rowBase + NHW + t]; }
  else       { xfr = xn.x; xfi = xn.y; }
  x[rowBase + t] = xfr; x[rowBase + NHW + t] = xfi;
  xc[rowBase + t] = xfr; xc[rowBase + NHW + t] = xfi;
  sA[t] = make_float2(xfr, xfi);
  fftp<-1, false>(sA, sB, stw, t, nullptr);
  t1[gb * NHW + gl * NW + t] = sA[t];
}

__global__ __launch_bounds__(NTHR) void k_out(const float* __restrict__ x,
                                              const double* __restrict__ hist_pres,
                                              const double* __restrict__ hist_dres,
                                              const double* __restrict__ pPa9,
                                              const double* __restrict__ pPb9,
                                              float* __restrict__ out) {
  __shared__ double sdot[16];
  const int t = threadIdx.x, bid = blockIdx.x;
  for (int i = bid * NTHR + t; i < NB * NC2; i += GRID * NTHR) out[i] = x[i];
  if (bid == 0) {
    double p9 = redParts(pPa9, sdot, t);
    double d9 = redParts(pPb9, sdot, t);
    if (t == 0) {
      int count = 0; bool done = false; float presO = 0.f, dresO = 0.f;
      for (int it = 0; it < 10; ++it) {
        double hp = (it == 9) ? p9 : hist_pres[it];
        double hd = (it == 9) ? d9 : hist_dres[it];
        if (!done) {
          count++;
          presO = sqrtf((float)hp);
          dresO = sqrtf((float)hd);
          done = (presO < 1e-4f) && (dresO < 1e-4f);
        }
      }
      out[NB * NC2 + 0] = (float)count;
      out[NB * NC2 + 1] = presO;
      out[NB * NC2 + 2] = dresO;
    }
  }
}

}  // namespace

extern "C" void kernel_launch(void* const* d_in, const int* in_sizes, int n_in,
                              void* d_out, int out_size, void* d_ws, size_t ws_size,
                              hipStream_t stream) {
  (void)in_sizes; (void)n_in; (void)out_size; (void)ws_size;
  const float* y = (const float*)d_in[0];
  const float* mask = (const float*)d_in[1];
  float* out = (float*)d_out;
  float* wsf = (float*)d_ws;

  double* dws = (double*)wsf;
  double* pRS       = dws;           // 1280
  double* pD0       = dws + 1280;
  double* pD1       = dws + 2560;
  double* pD2       = dws + 3840;
  double* pPa       = dws + 5120;    // 2 x 1280 (parity)
  double* pPb       = dws + 7680;    // 2 x 1280 (parity)
  double* hist_rs   = dws + 10240;   // 16
  double* hist_pres = dws + 10256;   // 16
  double* hist_dres = dws + 10272;   // 16 -> ends at 10288 doubles

  float* fb = wsf + 20576;           // after 10288 doubles
  float2* tw = (float2*)fb; fb += 640;
  float* misT = fb; fb += (size_t)NB * NHW;
  float2* t1 = (float2*)fb; fb += (size_t)2 * NB * NHW;
  float2* t2 = (float2*)fb; fb += (size_t)2 * NB * NHW;
  auto take = [&](size_t n) { float* ptr = fb; fb += n; return ptr; };
  float* x     = take((size_t)NB * NC2);
  float* xc    = take((size_t)NB * NC2);
  float* r     = take((size_t)NB * NC2);
  float* p     = take((size_t)NB * NC2);
  float* Ap    = take((size_t)NB * NC2);
  float* bdata = take((size_t)NB * NC2);
  float* u     = take((size_t)NB * 4 * NHW);
  float* v     = take((size_t)NB * 4 * NHW);
  float* un    = take((size_t)NB * 4 * NHW);
  float* vn    = take((size_t)NB * 4 * NHW);

  k_init<<<GRID, NTHR, 0, stream>>>(mask, misT, tw);
  k0a<<<GRID, NTHR, 0, stream>>>(y, mask, t1, t2, tw);
  k0b<<<GRID, NTHR, 0, stream>>>(t1, t2, x, bdata, tw);
  ka0<<<GRID, NTHR, 0, stream>>>(x, xc, u, v, t1, tw);

  for (int it = 0; it < 10; ++it) {
    int prevPar = (it + 1) & 1;  // (it-1)&1
    int curPar = it & 1;
    kb<<<GRID, NTHR, 0, stream>>>(t1, misT, un, vn, u, v,
                                  pPa + prevPar * 1280, pPb + prevPar * 1280,
                                  hist_pres, hist_dres, tw, it);
    kcd<<<GRID, NTHR, 0, stream>>>(t1, x, u, v, bdata, r, p, pRS, tw);
    ke<<<GRID, NTHR, 0, stream>>>(t1, misT, tw);
    kf<<<GRID, NTHR, 0, stream>>>(t1, p, r, Ap, pD0, pD1, pD2, tw);
    for (int k = 1; k < 10; ++k) {
      kd<<<GRID, NTHR, 0, stream>>>(xc, r, p, Ap, t1, pRS, pD0, pD1, pD2, hist_rs, tw, k);
      ke<<<GRID, NTHR, 0, stream>>>(t1, misT, tw);
      kf<<<GRID, NTHR, 0, stream>>>(t1, p, r, Ap, pD0, pD1, pD2, tw);
    }
    kh1<<<GRID, NTHR, 0, stream>>>(xc, p, v, t1, un, vn, pD0, hist_rs, pPa + curPar * 1280);
    kh2a<<<GRID, NTHR, 0, stream>>>(x, xc, t1, un, u, hist_pres, hist_dres,
                                    pPb + curPar * 1280, tw, it);
  }
  k_out<<<GRID, NTHR, 0, stream>>>(x, hist_pres, hist_dres, pPa + 1280, pPb + 1280, out);
}